// Round 5
// baseline (435.564 us; speedup 1.0000x reference)
//
#include <hip/hip_runtime.h>
#include <stdint.h>
#include <math.h>

#define T_SEQ 2048
#define HID   2880
#define QKV_D 5120   // 64*80
#define OD    4096   // 64 heads * 64
#define NQH   64
#define SM_SCALE 0.125f
#define LOG2E 1.44269504088896340736f
#define SSL (SM_SCALE * LOG2E)

typedef float f32x4 __attribute__((ext_vector_type(4)));
typedef float f32x16 __attribute__((ext_vector_type(16)));
typedef short bf16x8 __attribute__((ext_vector_type(8)));

__device__ __forceinline__ unsigned short f2bf(float f) {
  union { float f; unsigned u; } v; v.f = f;
  unsigned r = v.u + 0x7fffu + ((v.u >> 16) & 1u);
  return (unsigned short)(r >> 16);
}
__device__ __forceinline__ float bf2f(unsigned short h) {
  union { unsigned u; float f; } v; v.u = ((unsigned)h) << 16;
  return v.f;
}
__device__ __forceinline__ void gld_lds16(const void* g, void* l) {
  __builtin_amdgcn_global_load_lds(
      (const __attribute__((address_space(1))) unsigned int*)g,
      (__attribute__((address_space(3))) unsigned int*)l, 16, 0, 0);
}

// ---------------- RMSNorm: x (f32) -> t (bf16) ----------------
__global__ __launch_bounds__(256) void rmsnorm_k(const float* __restrict__ x,
                                                 const float* __restrict__ scale,
                                                 unsigned short* __restrict__ t) {
  int row = blockIdx.x;
  const float4* xr = (const float4*)(x + (size_t)row * HID); // 720 float4
  float s = 0.f;
  for (int i = threadIdx.x; i < 720; i += 256) {
    float4 a = xr[i];
    s += a.x * a.x + a.y * a.y + a.z * a.z + a.w * a.w;
  }
#pragma unroll
  for (int off = 32; off; off >>= 1) s += __shfl_down(s, off);
  __shared__ float wsum[4];
  int w = threadIdx.x >> 6, lane = threadIdx.x & 63;
  if (lane == 0) wsum[w] = s;
  __syncthreads();
  float tot = wsum[0] + wsum[1] + wsum[2] + wsum[3];
  float r = rsqrtf(tot / (float)HID + 1e-5f);
  const float4* sc4 = (const float4*)scale;
  ushort4* tr = (ushort4*)(t + (size_t)row * HID);
  for (int i = threadIdx.x; i < 720; i += 256) {
    float4 a = xr[i]; float4 b = sc4[i];
    ushort4 o;
    o.x = f2bf(a.x * r * b.x); o.y = f2bf(a.y * r * b.y);
    o.z = f2bf(a.z * r * b.z); o.w = f2bf(a.w * r * b.w);
    tr[i] = o;
  }
}

// ---------------- f32 -> bf16 convert ----------------
__global__ __launch_bounds__(256) void f2bf_k(const float* __restrict__ in,
                                              unsigned short* __restrict__ out, int n4) {
  int i = blockIdx.x * 256 + threadIdx.x;
  int stride = gridDim.x * 256;
  for (; i < n4; i += stride) {
    float4 a = ((const float4*)in)[i];
    ushort4 o;
    o.x = f2bf(a.x); o.y = f2bf(a.y); o.z = f2bf(a.z); o.w = f2bf(a.w);
    ((ushort4*)out)[i] = o;
  }
}

// ---------------- RoPE cos/sin table (YaRN-style NTK) ----------------
__global__ __launch_bounds__(256) void rope_tab_k(float* __restrict__ ct, float* __restrict__ st) {
  int idx = blockIdx.x * 256 + threadIdx.x; // T_SEQ*32
  int i = idx & 31, t = idx >> 5;
  double fi = (double)i;
  double freq = pow(150000.0, fi / 32.0);
  double lb = log(150000.0);
  double low  = 32.0 * log(4096.0 / (32.0 * 2.0 * M_PI)) / lb;
  double high = 32.0 * log(4096.0 / (1.0  * 2.0 * M_PI)) / lb;
  double interp = 1.0 / (32.0 * freq);
  double extrap = 1.0 / freq;
  double ramp = (fi - low) / (high - low);
  ramp = fmin(fmax(ramp, 0.0), 1.0);
  double mask = 1.0 - ramp;
  double invf = interp * (1.0 - mask) + extrap * mask;
  double conc = 0.1 * log(32.0) + 1.0;
  double th = (double)t * invf;
  ct[idx] = (float)(cos(th) * conc);
  st[idx] = (float)(sin(th) * conc);
}

// ---------------- RoPE apply to q,k (bf16 in-place) ----------------
__global__ __launch_bounds__(256) void rope_apply_k(unsigned short* __restrict__ qkv,
                                                    const float* __restrict__ ct,
                                                    const float* __restrict__ st) {
  int idx = blockIdx.x * 256 + threadIdx.x; // T_SEQ*72*32
  int i = idx & 31;
  int hh = (idx >> 5) % 72;
  int t = idx / (72 * 32);
  size_t base = (size_t)t * QKV_D + hh * 64 + i;
  float x1 = bf2f(qkv[base]), x2 = bf2f(qkv[base + 32]);
  float c = ct[t * 32 + i], s = st[t * 32 + i];
  qkv[base]      = f2bf(x1 * c - x2 * s);
  qkv[base + 32] = f2bf(x2 * c + x1 * s);
}

// ---------------- V transpose: vt[kvh][d][t] = V[t][kvh][d] ----------------
__global__ __launch_bounds__(256) void vtrans_k(const unsigned short* __restrict__ qkv,
                                                unsigned short* __restrict__ vt) {
  __shared__ unsigned short tile[64][72];
  int g = blockIdx.y;
  int t0 = blockIdx.x * 64;
  int tid = threadIdx.x;
#pragma unroll
  for (int p = 0; p < 2; ++p) {
    int ch = p * 256 + tid;
    int i = ch >> 3, j0 = (ch & 7) * 8;
    bf16x8 v = *(const bf16x8*)(qkv + (size_t)(t0 + i) * QKV_D + 4608 + g * 64 + j0);
    *(bf16x8*)&tile[i][j0] = v;
  }
  __syncthreads();
#pragma unroll
  for (int p = 0; p < 2; ++p) {
    int ch = p * 256 + tid;
    int j = ch >> 3, i0 = (ch & 7) * 8;
    union { unsigned short u[8]; bf16x8 v; } pk;
#pragma unroll
    for (int m = 0; m < 8; ++m) pk.u[m] = tile[i0 + m][j];
    *(bf16x8*)(vt + (size_t)(g * 64 + j) * T_SEQ + t0 + i0) = pk.v;
  }
}

// ---- GEMM v2: 128x128 tile, 8 waves, dbuf LDS + STAGE-ahead, XCD swizzle ----
template <bool FINAL>
__global__ __launch_bounds__(512, 4) void gemm8_k(const unsigned short* __restrict__ A,
                                                  const unsigned short* __restrict__ B,
                                                  const float* __restrict__ bias,
                                                  const float* __restrict__ resid,
                                                  unsigned short* __restrict__ Cb,
                                                  float* __restrict__ Cf,
                                                  int M, int N, int K) {
  __shared__ unsigned short As[2][128 * 32];
  __shared__ unsigned short Bs[2][128 * 32];
  int tid = threadIdx.x;
  int w = tid >> 6, lane = tid & 63;
  int g = lane >> 4, ln = lane & 15;
  int nwg = gridDim.x * gridDim.y;
  int lin = blockIdx.y * gridDim.x + blockIdx.x;
  int swz = (lin & 7) * (nwg >> 3) + (lin >> 3);
  int bx = swz % gridDim.x, by = swz / gridDim.x;
  int m0 = by * 128, n0 = bx * 128;
  int wr = w >> 1, wc = w & 1;  // 4x2 wave grid: 32 rows x 64 cols per wave
  f32x4 acc[2][4];
#pragma unroll
  for (int a = 0; a < 2; a++)
#pragma unroll
    for (int b = 0; b < 4; b++) acc[a][b] = (f32x4){0.f, 0.f, 0.f, 0.f};

  int srow = tid >> 2, scc = tid & 3;
  int sg = scc ^ (srow & 3);
  const unsigned short* gA = A + (size_t)(m0 + srow) * K + sg * 8;
  int rowB = n0 + srow; if (rowB > N - 1) rowB = N - 1;
  const unsigned short* gB = B + (size_t)rowB * K + sg * 8;

  int nt = K >> 5;
  gld_lds16(gA, &As[0][(w * 64) * 8]);
  gld_lds16(gB, &Bs[0][(w * 64) * 8]);
  __syncthreads();
  int cur = 0;
  for (int t = 0; t < nt; ++t) {
    if (t + 1 < nt) {
      int k0 = (t + 1) << 5;
      gld_lds16(gA + k0, &As[cur ^ 1][(w * 64) * 8]);
      gld_lds16(gB + k0, &Bs[cur ^ 1][(w * 64) * 8]);
    }
    bf16x8 af[2], bfr[4];
#pragma unroll
    for (int mi = 0; mi < 2; ++mi) {
      int rm = wr * 32 + mi * 16 + ln;
      int c = g ^ (rm & 3);
      af[mi] = *(const bf16x8*)&As[cur][rm * 32 + c * 8];
    }
#pragma unroll
    for (int ni = 0; ni < 4; ++ni) {
      int rn = wc * 64 + ni * 16 + ln;
      int c = g ^ (rn & 3);
      bfr[ni] = *(const bf16x8*)&Bs[cur][rn * 32 + c * 8];
    }
#pragma unroll
    for (int mi = 0; mi < 2; ++mi)
#pragma unroll
      for (int ni = 0; ni < 4; ++ni)
        acc[mi][ni] = __builtin_amdgcn_mfma_f32_16x16x32_bf16(af[mi], bfr[ni], acc[mi][ni], 0, 0, 0);
    __syncthreads();
    cur ^= 1;
  }
#pragma unroll
  for (int mi = 0; mi < 2; ++mi)
#pragma unroll
    for (int ni = 0; ni < 4; ++ni) {
      int colB = n0 + wc * 64 + ni * 16 + ln;
      if (colB >= N) continue;
      float bv = bias[colB];
#pragma unroll
      for (int r = 0; r < 4; ++r) {
        int rowC = m0 + wr * 32 + mi * 16 + g * 4 + r;
        float v = acc[mi][ni][r] + bv;
        if (FINAL) {
          Cf[(size_t)rowC * N + colB] = v + resid[(size_t)rowC * N + colB];
        } else {
          Cb[(size_t)rowC * N + colB] = f2bf(v);
        }
      }
    }
}

// ---------------- Flash attention v3: VALU-diet 32x32 swapped-operand ----------------
#define MAX8(V, B) fmaxf(fmaxf(fmaxf((V)[B], (V)[B + 1]), fmaxf((V)[B + 2], (V)[B + 3])), \
                         fmaxf(fmaxf((V)[B + 4], (V)[B + 5]), fmaxf((V)[B + 6], (V)[B + 7])))

__global__ __launch_bounds__(256) void attn2_k(const unsigned short* __restrict__ qkv,
                                               const unsigned short* __restrict__ vt,
                                               unsigned short* __restrict__ o) {
  __shared__ unsigned short Ks[2][64 * 64];
  __shared__ unsigned short Vs[2][64 * 64];
  int h = blockIdx.x;
  int qt = (int)gridDim.y - 1 - (int)blockIdx.y;  // long blocks first
  int tid = threadIdx.x;
  int w = tid >> 6, lane = tid & 63;
  int l31 = lane & 31, hi = lane >> 5;
  int qb0 = qt * 128;
  int q0w = qb0 + w * 32;
  int kvh = h >> 3;
  const unsigned short* kbase = qkv + 4096 + (size_t)kvh * 64;
  const unsigned short* vtb = vt + (size_t)kvh * 64 * T_SEQ;

  // Q fragments (B-operand of swapped QK^T)
  bf16x8 qf[4];
  {
    const unsigned short* qrow = qkv + (size_t)(q0w + l31) * QKV_D + h * 64;
#pragma unroll
    for (int dt = 0; dt < 4; ++dt)
      qf[dt] = *(const bf16x8*)(qrow + dt * 16 + hi * 8);
  }
  f32x16 oacc[2];
#pragma unroll
  for (int r = 0; r < 16; ++r) { oacc[0][r] = 0.f; oacc[1][r] = 0.f; }
  float m_run = -1e30f, l_run = 0.f;
  int nt = qt * 2 + 2;  // always even
  int q = q0w + l31;

  // persistent staging pointers (advance by 64 kv per tile)
  int ch = w * 64 + lane;                 // chunk 0..255
  int srow = ch >> 3, scc = ch & 7;
  int sgch = scc ^ (srow & 7);
  const unsigned short* gk  = kbase + (size_t)srow * QKV_D + sgch * 8;
  const unsigned short* gk2 = gk + (size_t)32 * QKV_D;
  const unsigned short* gv  = vtb + (size_t)srow * T_SEQ + sgch * 8;
  const unsigned short* gv2 = gv + (size_t)32 * T_SEQ;

  auto STAGE = [&](int buf) {
    unsigned short* Kd = &Ks[buf][0];
    unsigned short* Vd = &Vs[buf][0];
    gld_lds16(gk,  Kd + (w * 64) * 8);
    gld_lds16(gk2, Kd + (256 + w * 64) * 8);
    gld_lds16(gv,  Vd + (w * 64) * 8);
    gld_lds16(gv2, Vd + (256 + w * 64) * 8);
    gk += 64 * QKV_D; gk2 += 64 * QKV_D;
    gv += 64; gv2 += 64;
  };

  auto COMPUTE = [&](const unsigned short* K_, const unsigned short* V_, int kv0) {
    // S^T = K * Q^T  (two 32-k subtiles)
    f32x16 pa[2];
    __builtin_amdgcn_s_setprio(1);
#pragma unroll
    for (int kt2 = 0; kt2 < 2; ++kt2) {
      f32x16 acc;
#pragma unroll
      for (int r = 0; r < 16; ++r) acc[r] = 0.f;
      int rk = kt2 * 32 + l31;
#pragma unroll
      for (int dt = 0; dt < 4; ++dt) {
        int c = dt * 2 + hi;
        bf16x8 kf = *(const bf16x8*)&K_[rk * 64 + (c ^ (rk & 7)) * 8];
        acc = __builtin_amdgcn_mfma_f32_32x32x16_bf16(kf, qf[dt], acc, 0, 0, 0);
      }
      pa[kt2] = acc;
    }
    __builtin_amdgcn_s_setprio(0);
    // causal mask (raw domain), diag tiles only
    if (kv0 + 64 > q0w) {
#pragma unroll
      for (int kt2 = 0; kt2 < 2; ++kt2)
#pragma unroll
        for (int r = 0; r < 16; ++r) {
          int k = kv0 + kt2 * 32 + (r & 3) + 8 * (r >> 2) + 4 * hi;
          pa[kt2][r] = (k > q) ? -3.0e38f : pa[kt2][r];
        }
    }
    // max via tree (raw domain)
    float mx = fmaxf(fmaxf(MAX8(pa[0], 0), MAX8(pa[0], 8)),
                     fmaxf(MAX8(pa[1], 0), MAX8(pa[1], 8)));
    mx = fmaxf(mx, __shfl_xor(mx, 32));
    float mxs = mx * SSL;
    // defer-max (T13): rescale only when max grew past threshold
    if (!__all(mxs <= m_run + 8.f)) {
      float mnew = fmaxf(m_run, mxs);
      float alpha = exp2f(m_run - mnew);
      m_run = mnew;
      l_run *= alpha;
#pragma unroll
      for (int r = 0; r < 16; ++r) { oacc[0][r] *= alpha; oacc[1][r] *= alpha; }
    }
    // P = exp2(fma(pa, SSL, -m)), 4-way sum
    float negm = -m_run;
    float sa[4] = {0.f, 0.f, 0.f, 0.f};
#pragma unroll
    for (int kt2 = 0; kt2 < 2; ++kt2)
#pragma unroll
      for (int r = 0; r < 16; ++r) {
        float p = exp2f(fmaf(pa[kt2][r], SSL, negm));
        pa[kt2][r] = p;
        sa[r & 3] += p;
      }
    float sum = (sa[0] + sa[1]) + (sa[2] + sa[3]);
    sum += __shfl_xor(sum, 32);
    l_run += sum;
    // pack P -> bf16 pairs
    unsigned pw[16];
#pragma unroll
    for (int kt2 = 0; kt2 < 2; ++kt2)
#pragma unroll
      for (int i = 0; i < 8; ++i) {
        unsigned r_;
        asm("v_cvt_pk_bf16_f32 %0, %1, %2"
            : "=v"(r_) : "v"(pa[kt2][2 * i]), "v"(pa[kt2][2 * i + 1]));
        pw[kt2 * 8 + i] = r_;
      }
    // cross-half exchange via permlane32_swap: swap(p0,p2) -> (bw0,bw2)
    unsigned bw[2][2][4];
#pragma unroll
    for (int kt2 = 0; kt2 < 2; ++kt2)
#pragma unroll
      for (int a = 0; a < 2; ++a) {
        unsigned x0 = pw[kt2 * 8 + a * 4 + 0], y0 = pw[kt2 * 8 + a * 4 + 2];
        asm volatile("v_permlane32_swap_b32 %0, %1" : "+v"(x0), "+v"(y0));
        unsigned x1 = pw[kt2 * 8 + a * 4 + 1], y1 = pw[kt2 * 8 + a * 4 + 3];
        asm volatile("v_permlane32_swap_b32 %0, %1" : "+v"(x1), "+v"(y1));
        bw[kt2][a][0] = x0; bw[kt2][a][2] = y0;
        bw[kt2][a][1] = x1; bw[kt2][a][3] = y1;
      }
    // O^T += V^T * P^T
    __builtin_amdgcn_s_setprio(1);
#pragma unroll
    for (int db = 0; db < 2; ++db) {
      f32x16 acc = oacc[db];
      int rd = db * 32 + l31;
#pragma unroll
      for (int kt2 = 0; kt2 < 2; ++kt2)
#pragma unroll
        for (int a = 0; a < 2; ++a) {
          int c = kt2 * 4 + a * 2 + hi;
          bf16x8 vf = *(const bf16x8*)&V_[rd * 64 + (c ^ (rd & 7)) * 8];
          union { unsigned u[4]; bf16x8 v; } pun;
          pun.u[0] = bw[kt2][a][0]; pun.u[1] = bw[kt2][a][1];
          pun.u[2] = bw[kt2][a][2]; pun.u[3] = bw[kt2][a][3];
          acc = __builtin_amdgcn_mfma_f32_32x32x16_bf16(vf, pun.v, acc, 0, 0, 0);
        }
      oacc[db] = acc;
    }
    __builtin_amdgcn_s_setprio(0);
  };

  STAGE(0);
  __syncthreads();
  for (int t = 0; t < nt; t += 2) {
    STAGE(1);  // t+1 always < nt (nt even)
    if (t * 64 <= q0w + 31) COMPUTE(Ks[0], Vs[0], t * 64);
    __syncthreads();
    if (t + 2 < nt) STAGE(0);
    if ((t + 1) * 64 <= q0w + 31) COMPUTE(Ks[1], Vs[1], (t + 1) * 64);
    __syncthreads();
  }
  // epilogue: O[q][d] = O^T / l
  float inv = 1.f / l_run;
#pragma unroll
  for (int db = 0; db < 2; ++db)
#pragma unroll
    for (int r = 0; r < 16; r += 2) {
      int d = db * 32 + (r & 3) + 8 * (r >> 2) + 4 * hi;
      unsigned short lo_ = f2bf(oacc[db][r] * inv);
      unsigned short hi_ = f2bf(oacc[db][r + 1] * inv);
      unsigned u = (unsigned)lo_ | ((unsigned)hi_ << 16);
      *(unsigned*)(o + (size_t)q * OD + h * 64 + d) = u;
    }
}

extern "C" void kernel_launch(void* const* d_in, const int* in_sizes, int n_in,
                              void* d_out, int out_size, void* d_ws, size_t ws_size,
                              hipStream_t stream) {
  const float* x          = (const float*)d_in[0];
  const float* norm_scale = (const float*)d_in[1];
  const float* qkv_w      = (const float*)d_in[2];
  const float* qkv_b      = (const float*)d_in[3];
  const float* out_w      = (const float*)d_in[4];
  const float* out_b      = (const float*)d_in[5];
  float* out = (float*)d_out;

  char* ws = (char*)d_ws;
  size_t off = 0;
  auto alloc = [&](size_t bytes) {
    void* p = ws + off;
    off += (bytes + 255) & ~(size_t)255;
    return p;
  };
  unsigned short* t_bf = (unsigned short*)alloc((size_t)T_SEQ * HID * 2);
  unsigned short* wqkv = (unsigned short*)alloc((size_t)QKV_D * HID * 2);
  unsigned short* wout = (unsigned short*)alloc((size_t)HID * OD * 2);
  unsigned short* qkv  = (unsigned short*)alloc((size_t)T_SEQ * QKV_D * 2);
  unsigned short* obuf = (unsigned short*)alloc((size_t)T_SEQ * OD * 2);
  unsigned short* vtb  = (unsigned short*)alloc((size_t)8 * 64 * T_SEQ * 2);
  float* ct = (float*)alloc((size_t)T_SEQ * 32 * 4);
  float* st = (float*)alloc((size_t)T_SEQ * 32 * 4);

  rmsnorm_k<<<dim3(T_SEQ), dim3(256), 0, stream>>>(x, norm_scale, t_bf);
  f2bf_k<<<dim3(1024), dim3(256), 0, stream>>>(qkv_w, wqkv, QKV_D * HID / 4);
  f2bf_k<<<dim3(1024), dim3(256), 0, stream>>>(out_w, wout, HID * OD / 4);
  rope_tab_k<<<dim3(T_SEQ * 32 / 256), dim3(256), 0, stream>>>(ct, st);
  gemm8_k<false><<<dim3(QKV_D / 128, T_SEQ / 128), dim3(512), 0, stream>>>(
      t_bf, wqkv, qkv_b, nullptr, qkv, nullptr, T_SEQ, QKV_D, HID);
  rope_apply_k<<<dim3(T_SEQ * 72 * 32 / 256), dim3(256), 0, stream>>>(qkv, ct, st);
  vtrans_k<<<dim3(T_SEQ / 64, 8), dim3(256), 0, stream>>>(qkv, vtb);
  attn2_k<<<dim3(NQH, T_SEQ / 128), dim3(256), 0, stream>>>(qkv, vtb, obuf);
  gemm8_k<true><<<dim3((HID + 127) / 128, T_SEQ / 128), dim3(512), 0, stream>>>(
      obuf, wout, out_b, x, nullptr, out, T_SEQ, HID, OD);
}